// Round 13
// baseline (141.770 us; speedup 1.0000x reference)
//
#include <hip/hip_runtime.h>
#include <hip/hip_bf16.h>

#define N_ROWS 16384
#define M_ROWS 16384
#define DIM 256
#define JT 32           // y-cols per j-iter
#define NJ 64           // j-iters per block (JT*NJ = 2048-col chunk)

typedef __attribute__((ext_vector_type(4))) float f32x4;
typedef __attribute__((ext_vector_type(8))) short bf16x8;

__device__ inline unsigned enc_f(float f) {
  unsigned u = __float_as_uint(f);
  return (u & 0x80000000u) ? ~u : (u | 0x80000000u);
}
__device__ inline float dec_f(unsigned u) {
  unsigned b = (u & 0x80000000u) ? (u & 0x7FFFFFFFu) : ~u;
  return __uint_as_float(b);
}
__device__ inline unsigned short f2bf(float f) {
  unsigned u = __float_as_uint(f);
  u += 0x7FFFu + ((u >> 16) & 1u);
  return (unsigned short)(u >> 16);
}

// Fused prep: blocks [0,4096) convert x -> xb + x2 + rowmin init;
// blocks [4096,8192) convert y -> yb + (y2 - psi).
__global__ __launch_bounds__(256) void prep_kernel(
    const float* __restrict__ x, const float* __restrict__ y,
    const float* __restrict__ psi,
    unsigned short* __restrict__ xb, unsigned short* __restrict__ yb,
    float* __restrict__ x2, float* __restrict__ rj,
    unsigned int* __restrict__ rowmin) {
  int bid  = blockIdx.x;
  int isY  = bid >= (N_ROWS / 4);
  int rb   = isY ? bid - N_ROWS / 4 : bid;
  int row  = rb * 4 + (threadIdx.x >> 6);
  int lane = threadIdx.x & 63;
  const float* in = isY ? y : x;
  unsigned short* outb = isY ? yb : xb;
  const float4 v = *reinterpret_cast<const float4*>(in + (size_t)row * DIM + lane * 4);
  ushort4 b;
  b.x = f2bf(v.x); b.y = f2bf(v.y); b.z = f2bf(v.z); b.w = f2bf(v.w);
  *reinterpret_cast<ushort4*>(outb + (size_t)row * DIM + lane * 4) = b;
  float s = v.x * v.x + v.y * v.y + v.z * v.z + v.w * v.w;
#pragma unroll
  for (int m = 1; m < 64; m <<= 1) s += __shfl_xor(s, m, 64);
  if (lane == 0) {
    if (isY) rj[row] = s - psi[row];
    else { x2[row] = s; rowmin[row] = 0xFFFFFFFFu; }
  }
}

// M-streaming GEMM+min, 64 rows/wave, fragment-major LDS (R12), 3-deep ring,
// counted vmcnt(4). NEW: deferred double-accumulator fold — iter j's MFMAs
// interleave with iter j-1's fold VALU via sched_group_barrier singles
// {DS 2, (MFMA 1, VALU 1) x8} so matrix+VALU pipes co-issue within one wave.
__global__ __launch_bounds__(256, 2) void gemm_min_kernel(
    const unsigned short* __restrict__ xb, const unsigned short* __restrict__ yb,
    const float* __restrict__ rj, unsigned int* __restrict__ rowmin) {
  __shared__ unsigned short Bt[3][JT * DIM];  // 3 x 16 KiB

  const int bid    = blockIdx.x;       // 512 blocks, 2 per CU
  const int jchunk = bid & 7;          // == XCD id under round-robin dispatch
  const int strip  = bid >> 3;         // 0..63
  const int brow   = strip * 256;
  const int jbase0 = jchunk * (JT * NJ);

  const int tid = threadIdx.x;
  const int w = tid >> 6, lane = tid & 63;
  const int fr = lane & 15, g4 = lane >> 4;

  // ---- A fragments: rows brow + w*64 + m*16 + fr, k = ks*32 + g4*8.
  // No pin: compiler keeps what fits resident, remats the rest on the idle
  // VMEM pipe (R4-R6 showed residency is perf-neutral; budget goes to accs).
  bf16x8 afr[4][8];
  {
    const unsigned short* aBase = xb + (size_t)(brow + w * 64 + fr) * DIM + g4 * 8;
#pragma unroll
    for (int m = 0; m < 4; ++m)
#pragma unroll
      for (int ks = 0; ks < 8; ++ks)
        afr[m][ks] = *reinterpret_cast<const bf16x8*>(aBase + (size_t)(m * 16) * DIM + ks * 32);
  }
  __builtin_amdgcn_sched_barrier(0);

  // ---- staging: wave w stages chunks cc = w*4..w*4+3 (1KB each).
  // chunk cc = n*8 + ks; LDS[cc*1024 + lane*16] = yb[row: j*JT + n*16 + (lane>>2),
  // k: ks*32 + (lane&3)*8] -- lane-linear dest, permuted global source.
  const int srow = lane >> 2;          // 0..15 row within col-group
  const int scol = (lane & 3) * 8;     // k elems within 32-k slice

#define STAGE(buf, j)                                                            \
  {                                                                              \
    _Pragma("unroll")                                                            \
    for (int c = 0; c < 4; ++c) {                                                \
      const int cc = w * 4 + c;                                                  \
      const int sn = cc >> 3, sk = cc & 7;                                       \
      __builtin_amdgcn_global_load_lds(                                          \
          (const __attribute__((address_space(1))) void*)(                       \
              yb + (size_t)(jbase0 + (j) * JT + sn * 16 + srow) * DIM + sk * 32 + scol), \
          (__attribute__((address_space(3))) void*)(&Bt[(buf)][cc * 512]), 16, 0, 0); \
    }                                                                            \
  }

  STAGE(0, 0);
  STAGE(1, 1);

  const float* rjc = rj + jbase0;
  float mn[4][4];
#pragma unroll
  for (int m = 0; m < 4; ++m)
#pragma unroll
    for (int r = 0; r < 4; ++r) mn[m][r] = 3.4e38f;

  // Fragment address: chunk (n*8+ks)*512 shorts + fr*32 + g4*8 shorts.
#define BADDR(n, ks) (((n) * 8 + (ks)) * 512 + fr * 32 + g4 * 8)

  // ITER: compute iter J into ACCC while folding ACCP (iter J-1) under the
  // MFMA clusters. e = ks*4..ks*4+3 encodes (m=e>>3, n=(e>>2)&1, r=e&3).
#define ITER(J, ACCC, ACCP, RVC0, RVC1, RVP0, RVP1)                              \
  {                                                                              \
    if ((J) == NJ - 1) { asm volatile("s_waitcnt vmcnt(0)" ::: "memory"); }      \
    else               { asm volatile("s_waitcnt vmcnt(4)" ::: "memory"); }      \
    __builtin_amdgcn_sched_barrier(0);                                           \
    __builtin_amdgcn_s_barrier();                                                \
    __builtin_amdgcn_sched_barrier(0);                                           \
    RVC0 = rjc[(J) * JT + fr];                                                   \
    RVC1 = rjc[(J) * JT + 16 + fr];                                              \
    __builtin_amdgcn_sched_barrier(0);                                           \
    if ((J) + 2 < NJ) { int sb = rb + 2; if (sb >= 3) sb -= 3; STAGE(sb, (J) + 2); } \
    __builtin_amdgcn_sched_barrier(0);                                           \
    _Pragma("unroll")                                                            \
    for (int m = 0; m < 4; ++m)                                                  \
      _Pragma("unroll")                                                          \
      for (int n = 0; n < 2; ++n) ACCC[m][n] = (f32x4){0.f, 0.f, 0.f, 0.f};      \
    const unsigned short* B = &Bt[rb][0];                                        \
    bf16x8 pb0[3], pb1[3];                                                       \
    pb0[0] = *reinterpret_cast<const bf16x8*>(&B[BADDR(0, 0)]);                  \
    pb1[0] = *reinterpret_cast<const bf16x8*>(&B[BADDR(1, 0)]);                  \
    pb0[1] = *reinterpret_cast<const bf16x8*>(&B[BADDR(0, 1)]);                  \
    pb1[1] = *reinterpret_cast<const bf16x8*>(&B[BADDR(1, 1)]);                  \
    __builtin_amdgcn_s_setprio(1);                                               \
    __builtin_amdgcn_sched_barrier(0);                                           \
    _Pragma("unroll")                                                            \
    for (int ks = 0; ks < 8; ++ks) {                                             \
      const int cs = ks % 3, ns = (ks + 2) % 3;                                  \
      if (ks < 6) {                                                              \
        pb0[ns] = *reinterpret_cast<const bf16x8*>(&B[BADDR(0, ks + 2)]);        \
        pb1[ns] = *reinterpret_cast<const bf16x8*>(&B[BADDR(1, ks + 2)]);        \
      }                                                                          \
      _Pragma("unroll")                                                          \
      for (int m = 0; m < 4; ++m) {                                              \
        ACCC[m][0] = __builtin_amdgcn_mfma_f32_16x16x32_bf16(afr[m][ks], pb0[cs], ACCC[m][0], 0, 0, 0); \
        ACCC[m][1] = __builtin_amdgcn_mfma_f32_16x16x32_bf16(afr[m][ks], pb1[cs], ACCC[m][1], 0, 0, 0); \
      }                                                                          \
      _Pragma("unroll")                                                          \
      for (int e = (ks) * 4; e < (ks) * 4 + 4; ++e) {                            \
        const int fm = e >> 3, fn = (e >> 2) & 1, fq = e & 3;                    \
        mn[fm][fq] = fminf(mn[fm][fq],                                           \
            fmaf(-2.f, ACCP[fm][fn][fq], fn ? (RVP1) : (RVP0)));                 \
      }                                                                          \
      if (ks < 6) __builtin_amdgcn_sched_group_barrier(0x100, 2, 0);             \
      _Pragma("unroll")                                                          \
      for (int q = 0; q < 8; ++q) {                                              \
        __builtin_amdgcn_sched_group_barrier(0x008, 1, 0);                       \
        __builtin_amdgcn_sched_group_barrier(0x002, 1, 0);                       \
      }                                                                          \
    }                                                                            \
    __builtin_amdgcn_sched_barrier(0);                                           \
    __builtin_amdgcn_s_setprio(0);                                               \
    rb = rb + 1; if (rb >= 3) rb -= 3;                                           \
  }

  f32x4 accA[4][2], accB[4][2];
  float rvA0, rvA1, rvB0, rvB1;
  // dummy prev state: fold of accB at j=0 yields 3.0e38 (harmless vs min)
#pragma unroll
  for (int m = 0; m < 4; ++m)
#pragma unroll
    for (int n = 0; n < 2; ++n) accB[m][n] = (f32x4){0.f, 0.f, 0.f, 0.f};
  rvB0 = 3.0e38f; rvB1 = 3.0e38f;

  int rb = 0;  // ring read index
#pragma unroll 1
  for (int jj = 0; jj < NJ; jj += 2) {
    ITER(jj,     accA, accB, rvA0, rvA1, rvB0, rvB1);
    ITER(jj + 1, accB, accA, rvB0, rvB1, rvA0, rvA1);
  }
  // epilogue: fold the final iter's acc (accB, j = NJ-1)
#pragma unroll
  for (int m = 0; m < 4; ++m)
#pragma unroll
    for (int n = 0; n < 2; ++n)
#pragma unroll
      for (int r = 0; r < 4; ++r)
        mn[m][r] = fminf(mn[m][r], fmaf(-2.f, accB[m][n][r], n ? rvB1 : rvB0));
#undef ITER
#undef BADDR
#undef STAGE

  // Row-min over chunk: reduce min over the 16 fr-lanes, then one atomic per row.
#pragma unroll
  for (int m = 0; m < 4; ++m)
#pragma unroll
    for (int r = 0; r < 4; ++r) {
      float v = mn[m][r];
#pragma unroll
      for (int s = 1; s < 16; s <<= 1) v = fminf(v, __shfl_xor(v, s, 64));
      if (fr == 0) {
        int row = brow + w * 64 + m * 16 + g4 * 4 + r;
        atomicMin(&rowmin[row], enc_f(v));
      }
    }
}

__global__ __launch_bounds__(256) void finish_kernel(
    const float* __restrict__ x2, const unsigned int* __restrict__ rowmin,
    const float* __restrict__ psi, float* __restrict__ out) {
  int tid = threadIdx.x;
  double s0 = 0.0, s1 = 0.0;
  for (int i = tid; i < N_ROWS; i += 256) {
    s0 += (double)x2[i] + (double)dec_f(rowmin[i]);
    s1 += (double)psi[i];
  }
  __shared__ double sm0[4], sm1[4];
#pragma unroll
  for (int m = 1; m < 64; m <<= 1) { s0 += __shfl_xor(s0, m, 64); s1 += __shfl_xor(s1, m, 64); }
  if ((tid & 63) == 0) { sm0[tid >> 6] = s0; sm1[tid >> 6] = s1; }
  __syncthreads();
  if (tid == 0) {
    out[0] = (float)((sm0[0] + sm0[1] + sm0[2] + sm0[3]) / (double)N_ROWS);
    out[1] = (float)((sm1[0] + sm1[1] + sm1[2] + sm1[3]) / (double)M_ROWS);
  }
}

extern "C" void kernel_launch(void* const* d_in, const int* in_sizes, int n_in,
                              void* d_out, int out_size, void* d_ws, size_t ws_size,
                              hipStream_t stream) {
  const float* x   = (const float*)d_in[0];
  const float* y   = (const float*)d_in[1];
  const float* psi = (const float*)d_in[2];
  float* out = (float*)d_out;

  char* ws = (char*)d_ws;
  unsigned short* xb = (unsigned short*)ws;                                  // 8 MB
  unsigned short* yb = (unsigned short*)(ws + (size_t)N_ROWS * DIM * 2);     // 8 MB
  float* x2 = (float*)(ws + (size_t)(N_ROWS + M_ROWS) * DIM * 2);            // 64 KB
  float* rj = x2 + N_ROWS;                                                   // 64 KB (y2 - psi)
  unsigned int* rowmin = (unsigned int*)(rj + M_ROWS);                       // 64 KB

  prep_kernel<<<(N_ROWS + M_ROWS) / 4, 256, 0, stream>>>(x, y, psi, xb, yb, x2, rj, rowmin);
  gemm_min_kernel<<<(N_ROWS / 256) * 8, 256, 0, stream>>>(xb, yb, rj, rowmin);
  finish_kernel<<<1, 256, 0, stream>>>(x2, rowmin, psi, out);
}